// Round 5
// baseline (344.276 us; speedup 1.0000x reference)
//
#include <hip/hip_runtime.h>
#include <hip/hip_bf16.h>
#include <math.h>

// OLMoE sparse MoE block. fp32 storage, bf16 MFMA compute (32x32x16).
// T=1024, H=2048, I=1024, E=8, top-2, unweighted combine.
// Round 11: distance-3 B-loads (3 reg sets), distance-2 A-DMA (3 LDS bufs),
// 6-phase unrolled loop with literal buffer indices, steady-state
// s_waitcnt vmcnt(20) (drain only the 1.3-phase-old DMAs), plus
// conflict-free LDS swizzles on A (row&7 ^ row>>3) and B (k ^ n>>3 XOR).

#define NT 1024
#define HD 2048
#define ID 1024
#define NE 8
#define MAXTILES 24
#define BPITCH 72

typedef __bf16 v8bf __attribute__((ext_vector_type(8)));
typedef __bf16 v4bf __attribute__((ext_vector_type(4)));
typedef float v16f __attribute__((ext_vector_type(16)));

__device__ __forceinline__ v8bf cvt8(float4 a, float4 b) {
    v8bf v;
    v[0] = (__bf16)a.x; v[1] = (__bf16)a.y; v[2] = (__bf16)a.z; v[3] = (__bf16)a.w;
    v[4] = (__bf16)b.x; v[5] = (__bf16)b.y; v[6] = (__bf16)b.z; v[7] = (__bf16)b.w;
    return v;
}

__device__ __forceinline__ void gload16(const void* g, void* l) {
    __builtin_amdgcn_global_load_lds(
        (const __attribute__((address_space(1))) unsigned int*)g,
        (__attribute__((address_space(3))) unsigned int*)l, 16, 0, 0);
}

// ---------------- x -> bf16 ----------------
__global__ __launch_bounds__(256) void cvtx_kernel(
    const float* __restrict__ x, __bf16* __restrict__ xb)
{
    int t = blockIdx.x * 256 + threadIdx.x;
    const float4* p = (const float4*)x + (size_t)t * 2;
    float4 a = p[0], b = p[1];
    *(v8bf*)(xb + (size_t)t * 8) = cvt8(a, b);
}

// ---------------- router: one wave per token ----------------
__global__ __launch_bounds__(256) void router_kernel(
    const float* __restrict__ x, const float* __restrict__ gw,
    float* __restrict__ logits_out, int* __restrict__ topids, int* __restrict__ counts)
{
    int wv = threadIdx.x >> 6, ln = threadIdx.x & 63;
    int t = blockIdx.x * 4 + wv;
    const float* xr = x + (size_t)t * HD + ln * 32;
    float4 xv[8];
#pragma unroll
    for (int i = 0; i < 8; i++) xv[i] = *(const float4*)(xr + i * 4);

    float lg[NE];
#pragma unroll
    for (int e = 0; e < NE; e++) {
        const float* wr = gw + (size_t)e * HD + ln * 32;
        float s = 0.f;
#pragma unroll
        for (int i = 0; i < 8; i++) {
            float4 w4 = *(const float4*)(wr + i * 4);
            s += xv[i].x * w4.x + xv[i].y * w4.y + xv[i].z * w4.z + xv[i].w * w4.w;
        }
#pragma unroll
        for (int off = 32; off > 0; off >>= 1) s += __shfl_down(s, off, 64);
        lg[e] = s;
    }
    if (ln == 0) {
#pragma unroll
        for (int e = 0; e < NE; e++) logits_out[t * NE + e] = lg[e];
        int i1 = 0;
        for (int e = 1; e < NE; e++) if (lg[e] > lg[i1]) i1 = e;
        int i2 = -1;
        for (int e = 0; e < NE; e++) {
            if (e == i1) continue;
            if (i2 < 0 || lg[e] > lg[i2]) i2 = e;
        }
        topids[t * 2 + 0] = i1;
        topids[t * 2 + 1] = i2;
        atomicAdd(&counts[i1], 1);
        atomicAdd(&counts[i2], 1);
    }
}

// ---------------- scan + tile table ----------------
__global__ void scan_kernel(const int* __restrict__ counts, int* __restrict__ base,
                            int* __restrict__ cursor, int* __restrict__ tile_e,
                            int* __restrict__ tile_m)
{
    if (threadIdx.x == 0 && blockIdx.x == 0) {
        int s = 0, nt = 0;
        for (int e = 0; e < NE; e++) {
            base[e] = s; cursor[e] = s;
            for (int m0 = 0; m0 < counts[e]; m0 += 128) {
                tile_e[nt] = e; tile_m[nt] = m0; nt++;
            }
            s += counts[e];
        }
        for (int i = nt; i < MAXTILES; i++) tile_e[i] = -1;
    }
}

__global__ void assign_kernel(const int* __restrict__ topids, int* __restrict__ cursor,
                              int* __restrict__ rowtok, int* __restrict__ toppos)
{
    int t = blockIdx.x * blockDim.x + threadIdx.x;
    if (t < NT) {
#pragma unroll
        for (int s = 0; s < 2; s++) {
            int e = topids[t * 2 + s];
            int pos = atomicAdd(&cursor[e], 1);
            rowtok[pos] = t;
            toppos[t * 2 + s] = pos;
        }
    }
}

// ---------------- GEMM1: h = silu(X Wg) * (X Wu) ----------------
// tile M128 x N64, BK=64, 4 waves. A: DMA (dist-2, 3 bufs, swizzled).
// B: reg-staged fp32->bf16 (dist-3, 3 reg sets), k-XOR swizzle.

#define G1_BLOAD(STEP, S) do { \
    const float* pg_ = wge + (size_t)((STEP) * 64 + kp) * ID; \
    const float* pu_ = wue + (size_t)((STEP) * 64 + kp) * ID; \
    _Pragma("unroll") for (int i_ = 0; i_ < 4; i_++) { \
        rg[S][i_] = *(const float4*)(pg_ + (size_t)i_ * ID); \
        ru[S][i_] = *(const float4*)(pu_ + (size_t)i_ * ID); } \
} while (0)

#define G1_BSTORE(BB, S) do { \
    const float* gf_ = (const float*)&rg[S][0]; \
    const float* uf_ = (const float*)&ru[S][0]; \
    _Pragma("unroll") for (int j_ = 0; j_ < 4; j_++) { \
        int col_ = kp ^ ((((bn + j_) >> 3) & 3) << 3); \
        v4bf pg_, pu_; \
        _Pragma("unroll") for (int i_ = 0; i_ < 4; i_++) { \
            pg_[i_] = (__bf16)gf_[i_ * 4 + j_]; \
            pu_[i_] = (__bf16)uf_[i_ * 4 + j_]; } \
        *(v4bf*)&Bg[BB][bn + j_][col_] = pg_; \
        *(v4bf*)&Bu[BB][bn + j_][col_] = pu_; } \
} while (0)

#define G1_AISSUE(AB, STEP) do { \
    _Pragma("unroll") for (int i_ = 0; i_ < 4; i_++) \
        gload16(aptr[i_] + (STEP) * 64, &Ald[AB][w * 32 + i_ * 8][0]); \
} while (0)

#define G1_MFMA(AB, BB) do { \
    _Pragma("unroll") for (int kh_ = 0; kh_ < 4; kh_++) { \
        int kb_ = kh_ * 16 + hh * 8; \
        int kea_ = kb_ ^ aswz; \
        int keb_ = kb_ ^ bswz; \
        v8bf af0_ = *(const v8bf*)&Ald[AB][wm + ml][kea_]; \
        v8bf af1_ = *(const v8bf*)&Ald[AB][wm + 32 + ml][kea_]; \
        v8bf bg_ = *(const v8bf*)&Bg[BB][wn + ml][keb_]; \
        v8bf bu_ = *(const v8bf*)&Bu[BB][wn + ml][keb_]; \
        accg0 = __builtin_amdgcn_mfma_f32_32x32x16_bf16(af0_, bg_, accg0, 0, 0, 0); \
        accg1 = __builtin_amdgcn_mfma_f32_32x32x16_bf16(af1_, bg_, accg1, 0, 0, 0); \
        accu0 = __builtin_amdgcn_mfma_f32_32x32x16_bf16(af0_, bu_, accu0, 0, 0, 0); \
        accu1 = __builtin_amdgcn_mfma_f32_32x32x16_bf16(af1_, bu_, accu1, 0, 0, 0); } \
} while (0)

#define G1PHASE(S, AC, AP, BSS, BSL, BBS, BBM) \
  if ((S) < NS) { \
    if ((S) + 1 < NS) G1_BSTORE(BBS, BSS); \
    if ((S) + 2 < NS) G1_AISSUE(AP, (S) + 2); \
    __builtin_amdgcn_sched_barrier(0); \
    if ((S) + 3 < NS) G1_BLOAD((S) + 3, BSL); \
    G1_MFMA(AC, BBM); \
    if ((S) + 3 < NS) { asm volatile("s_waitcnt vmcnt(20) lgkmcnt(0)" ::: "memory"); } \
    else if ((S) + 2 < NS) { asm volatile("s_waitcnt vmcnt(12) lgkmcnt(0)" ::: "memory"); } \
    else { asm volatile("s_waitcnt vmcnt(0) lgkmcnt(0)" ::: "memory"); } \
    __builtin_amdgcn_s_barrier(); \
  }

__global__ __launch_bounds__(256) void gemm1_kernel(
    const __bf16* __restrict__ xb, const float* __restrict__ wg, const float* __restrict__ wu,
    const int* __restrict__ counts, const int* __restrict__ basev, const int* __restrict__ rowtok,
    const int* __restrict__ tile_e, const int* __restrict__ tile_m,
    __bf16* __restrict__ hbuf)
{
    int ti = blockIdx.y;
    int e = tile_e[ti];
    if (e < 0) return;
    int m0 = tile_m[ti];
    int cnt = counts[e];
    int n0 = blockIdx.x * 64;
    int base = basev[e];

    __shared__ __align__(16) __bf16 Ald[3][128][64];
    __shared__ __align__(16) __bf16 Bg[2][64][BPITCH];
    __shared__ __align__(16) __bf16 Bu[2][64][BPITCH];

    int tid = threadIdx.x;
    int w = tid >> 6, ln = tid & 63, ml = ln & 31, hh = ln >> 5;
    int wm = (w & 1) * 64, wn = (w >> 1) * 32;
    int aswz = ((ml & 7) ^ ((ml >> 3) & 3)) << 3;
    int bswz = ((ml >> 3) & 3) << 3;

    // A staging: per wave 4 DMA instrs, each covers 8 rows (128B/row).
    // LDS dest linear; source chunk pre-swizzled: seg ^ (row&7) ^ ((row>>3)&3).
    int lrow8 = ln >> 3, seg = ln & 7;
    const __bf16* aptr[4];
#pragma unroll
    for (int i = 0; i < 4; i++) {
        int idx = m0 + w * 32 + i * 8 + lrow8;
        int tok = (idx < cnt) ? rowtok[base + idx] : 0;
        int gseg = seg ^ lrow8 ^ (i & 3);
        aptr[i] = xb + (size_t)tok * HD + gseg * 8;
    }

    int s_ = tid & 15, P = tid >> 4;
    int bn = s_ * 4, kp = P * 4;
    const float* wge = wg + (size_t)e * HD * ID + n0 + bn;
    const float* wue = wu + (size_t)e * HD * ID + n0 + bn;

    float4 rg[3][4], ru[3][4];
    v16f accg0, accg1, accu0, accu1;
#pragma unroll
    for (int r = 0; r < 16; r++) { accg0[r] = 0.f; accg1[r] = 0.f; accu0[r] = 0.f; accu1[r] = 0.f; }

    const int NS = HD / 64;  // 32 phases

    // prologue: queue -> [bl1(8)][dma1(4)][bl2(8)] = steady invariant at s=0
    G1_BLOAD(0, 0);
    G1_AISSUE(0, 0);
    __builtin_amdgcn_sched_barrier(0);
    G1_BLOAD(1, 1);
    G1_BSTORE(0, 0);
    G1_AISSUE(1, 1);
    __builtin_amdgcn_sched_barrier(0);
    G1_BLOAD(2, 2);
    asm volatile("s_waitcnt vmcnt(20) lgkmcnt(0)" ::: "memory");
    __builtin_amdgcn_s_barrier();

    for (int it = 0; it < NS; it += 6) {
        G1PHASE(it + 0, 0, 2, 1, 0, 1, 0);
        G1PHASE(it + 1, 1, 0, 2, 1, 0, 1);
        G1PHASE(it + 2, 2, 1, 0, 2, 1, 0);
        G1PHASE(it + 3, 0, 2, 1, 0, 0, 1);
        G1PHASE(it + 4, 1, 0, 2, 1, 1, 0);
        G1PHASE(it + 5, 2, 1, 0, 2, 0, 1);
    }

#pragma unroll
    for (int r = 0; r < 16; r++) {
        int dr = (r & 3) + 8 * (r >> 2) + 4 * hh;
        int row0 = wm + dr, row1 = wm + 32 + dr;
        int col = n0 + wn + ml;
        if (m0 + row0 < cnt) {
            float g = accg0[r], u = accu0[r];
            hbuf[(size_t)(base + m0 + row0) * ID + col] = (__bf16)(g / (1.f + __expf(-g)) * u);
        }
        if (m0 + row1 < cnt) {
            float g = accg1[r], u = accu1[r];
            hbuf[(size_t)(base + m0 + row1) * ID + col] = (__bf16)(g / (1.f + __expf(-g)) * u);
        }
    }
}

// ---------------- GEMM2: y = h Wd ----------------
// tile M128 x N128, BK=64, 4 waves (each 64x64 out). Same pipeline.

#define G2_BLOAD(STEP, S) do { \
    const float* p0_ = wde + (size_t)((STEP) * 64 + kp) * HD; \
    _Pragma("unroll") for (int i_ = 0; i_ < 8; i_++) \
        rd[S][i_] = *(const float4*)(p0_ + (size_t)i_ * HD); \
} while (0)

#define G2_BSTORE(BB, S) do { \
    const float* df_ = (const float*)&rd[S][0]; \
    _Pragma("unroll") for (int j_ = 0; j_ < 4; j_++) { \
        int col_ = kp ^ ((((bn + j_) >> 3) & 3) << 3); \
        v8bf pd_; \
        _Pragma("unroll") for (int i_ = 0; i_ < 8; i_++) pd_[i_] = (__bf16)df_[i_ * 4 + j_]; \
        *(v8bf*)&Bd[BB][bn + j_][col_] = pd_; } \
} while (0)

#define G2_AISSUE(AB, STEP) do { \
    _Pragma("unroll") for (int i_ = 0; i_ < 4; i_++) \
        gload16(aptr[i_] + (STEP) * 64, &Ald[AB][w * 32 + i_ * 8][0]); \
} while (0)

#define G2_MFMA(AB, BB) do { \
    _Pragma("unroll") for (int kh_ = 0; kh_ < 4; kh_++) { \
        int kb_ = kh_ * 16 + hh * 8; \
        int kea_ = kb_ ^ aswz; \
        int keb_ = kb_ ^ bswz; \
        v8bf af0_ = *(const v8bf*)&Ald[AB][wm + ml][kea_]; \
        v8bf af1_ = *(const v8bf*)&Ald[AB][wm + 32 + ml][kea_]; \
        v8bf bf0_ = *(const v8bf*)&Bd[BB][wn + ml][keb_]; \
        v8bf bf1_ = *(const v8bf*)&Bd[BB][wn + 32 + ml][keb_]; \
        acc00 = __builtin_amdgcn_mfma_f32_32x32x16_bf16(af0_, bf0_, acc00, 0, 0, 0); \
        acc10 = __builtin_amdgcn_mfma_f32_32x32x16_bf16(af1_, bf0_, acc10, 0, 0, 0); \
        acc01 = __builtin_amdgcn_mfma_f32_32x32x16_bf16(af0_, bf1_, acc01, 0, 0, 0); \
        acc11 = __builtin_amdgcn_mfma_f32_32x32x16_bf16(af1_, bf1_, acc11, 0, 0, 0); } \
} while (0)

#define G2PHASE(S, AC, AP, BSS, BSL, BBS, BBM) \
  if ((S) < NS) { \
    if ((S) + 1 < NS) G2_BSTORE(BBS, BSS); \
    if ((S) + 2 < NS) G2_AISSUE(AP, (S) + 2); \
    __builtin_amdgcn_sched_barrier(0); \
    if ((S) + 3 < NS) G2_BLOAD((S) + 3, BSL); \
    G2_MFMA(AC, BBM); \
    if ((S) + 3 < NS) { asm volatile("s_waitcnt vmcnt(20) lgkmcnt(0)" ::: "memory"); } \
    else if ((S) + 2 < NS) { asm volatile("s_waitcnt vmcnt(12) lgkmcnt(0)" ::: "memory"); } \
    else { asm volatile("s_waitcnt vmcnt(0) lgkmcnt(0)" ::: "memory"); } \
    __builtin_amdgcn_s_barrier(); \
  }

__global__ __launch_bounds__(256) void gemm2_kernel(
    const __bf16* __restrict__ hbuf, const float* __restrict__ wd,
    const int* __restrict__ counts, const int* __restrict__ basev,
    const int* __restrict__ tile_e, const int* __restrict__ tile_m,
    __bf16* __restrict__ ybuf)
{
    int ti = blockIdx.y;
    int e = tile_e[ti];
    if (e < 0) return;
    int m0 = tile_m[ti];
    int cnt = counts[e];
    int n0 = blockIdx.x * 128;
    int base = basev[e];

    __shared__ __align__(16) __bf16 Ald[3][128][64];
    __shared__ __align__(16) __bf16 Bd[2][128][BPITCH];

    int tid = threadIdx.x;
    int w = tid >> 6, ln = tid & 63, ml = ln & 31, hh = ln >> 5;
    int wm = (w & 1) * 64, wn = (w >> 1) * 64;
    int aswz = ((ml & 7) ^ ((ml >> 3) & 3)) << 3;
    int bswz = ((ml >> 3) & 3) << 3;

    int lrow8 = ln >> 3, seg = ln & 7;
    const __bf16* aptr[4];
#pragma unroll
    for (int i = 0; i < 4; i++) {
        int idx = m0 + w * 32 + i * 8 + lrow8;
        int hr = base + (idx < cnt ? idx : cnt - 1);
        int gseg = seg ^ lrow8 ^ (i & 3);
        aptr[i] = hbuf + (size_t)hr * ID + gseg * 8;
    }

    int s_ = tid & 31, P = tid >> 5;
    int bn = s_ * 4, kp = P * 8;
    const float* wde = wd + (size_t)e * ID * HD + n0 + bn;

    float4 rd[3][8];
    v16f acc00, acc10, acc01, acc11;
#pragma unroll
    for (int r = 0; r < 16; r++) { acc00[r] = 0.f; acc10[r] = 0.f; acc01[r] = 0.f; acc11[r] = 0.f; }

    const int NS = ID / 64;  // 16 phases

    G2_BLOAD(0, 0);
    G2_AISSUE(0, 0);
    __builtin_amdgcn_sched_barrier(0);
    G2_BLOAD(1, 1);
    G2_BSTORE(0, 0);
    G2_AISSUE(1, 1);
    __builtin_amdgcn_sched_barrier(0);
    G2_BLOAD(2, 2);
    asm volatile("s_waitcnt vmcnt(20) lgkmcnt(0)" ::: "memory");
    __builtin_amdgcn_s_barrier();

    for (int it = 0; it < NS; it += 6) {
        G2PHASE(it + 0, 0, 2, 1, 0, 1, 0);
        G2PHASE(it + 1, 1, 0, 2, 1, 0, 1);
        G2PHASE(it + 2, 2, 1, 0, 2, 1, 0);
        G2PHASE(it + 3, 0, 2, 1, 0, 0, 1);
        G2PHASE(it + 4, 1, 0, 2, 1, 1, 0);
        G2PHASE(it + 5, 2, 1, 0, 2, 0, 1);
    }

#pragma unroll
    for (int r = 0; r < 16; r++) {
        int dr = (r & 3) + 8 * (r >> 2) + 4 * hh;
        int row0 = wm + dr, row1 = wm + 32 + dr;
        if (m0 + row0 < cnt) {
            size_t o = (size_t)(base + m0 + row0) * HD + n0 + wn;
            ybuf[o + ml]      = (__bf16)acc00[r];
            ybuf[o + 32 + ml] = (__bf16)acc01[r];
        }
        if (m0 + row1 < cnt) {
            size_t o = (size_t)(base + m0 + row1) * HD + n0 + wn;
            ybuf[o + ml]      = (__bf16)acc10[r];
            ybuf[o + 32 + ml] = (__bf16)acc11[r];
        }
    }
}

// ---------------- combine ----------------
__global__ __launch_bounds__(256) void combine_kernel(
    const __bf16* __restrict__ ybuf, const int* __restrict__ toppos, float* __restrict__ out)
{
    int t = blockIdx.x;
    int tid = threadIdx.x;
    int p0 = toppos[t * 2 + 0];
    int p1 = toppos[t * 2 + 1];
    v8bf a = ((const v8bf*)(ybuf + (size_t)p0 * HD))[tid];
    v8bf b = ((const v8bf*)(ybuf + (size_t)p1 * HD))[tid];
    float4 o0, o1;
    o0.x = (float)a[0] + (float)b[0];
    o0.y = (float)a[1] + (float)b[1];
    o0.z = (float)a[2] + (float)b[2];
    o0.w = (float)a[3] + (float)b[3];
    o1.x = (float)a[4] + (float)b[4];
    o1.y = (float)a[5] + (float)b[5];
    o1.z = (float)a[6] + (float)b[6];
    o1.w = (float)a[7] + (float)b[7];
    float* orow = out + (size_t)t * HD + tid * 8;
    *(float4*)orow = o0;
    *(float4*)(orow + 4) = o1;
}

extern "C" void kernel_launch(void* const* d_in, const int* in_sizes, int n_in,
                              void* d_out, int out_size, void* d_ws, size_t ws_size,
                              hipStream_t stream)
{
    const float* x  = (const float*)d_in[0];
    const float* gw = (const float*)d_in[1];
    const float* wg = (const float*)d_in[2];
    const float* wu = (const float*)d_in[3];
    const float* wd = (const float*)d_in[4];
    float* out = (float*)d_out;
    float* logits = out + (size_t)NT * HD;

    char* ws = (char*)d_ws;
    int* counts = (int*)(ws + 0);
    int* base   = (int*)(ws + 64);
    int* cursor = (int*)(ws + 128);
    int* tile_e = (int*)(ws + 256);
    int* tile_m = (int*)(ws + 384);
    int* topids = (int*)(ws + 1024);
    int* toppos = (int*)(ws + 1024 + 8192);
    int* rowtok = (int*)(ws + 1024 + 16384);
    __bf16* hbuf = (__bf16*)(ws + 32768);                            // [2048,1024] bf16 = 4 MB
    __bf16* ybuf = (__bf16*)(ws + 32768 + (size_t)2048 * ID * 2);    // [2048,2048] bf16 = 8 MB
    __bf16* xb   = (__bf16*)(ws + 32768 + (size_t)2048 * ID * 2 + (size_t)2048 * HD * 2);  // 4 MB

    hipMemsetAsync(ws, 0, 256, stream);
    cvtx_kernel<<<NT * HD / (256 * 8), 256, 0, stream>>>(x, xb);
    router_kernel<<<NT / 4, 256, 0, stream>>>(x, gw, logits, topids, counts);
    scan_kernel<<<1, 64, 0, stream>>>(counts, base, cursor, tile_e, tile_m);
    assign_kernel<<<4, 256, 0, stream>>>(topids, cursor, rowtok, toppos);
    gemm1_kernel<<<dim3(ID / 64, MAXTILES), 256, 0, stream>>>(xb, wg, wu, counts, base, rowtok, tile_e, tile_m, hbuf);
    gemm2_kernel<<<dim3(HD / 128, MAXTILES), 256, 0, stream>>>(hbuf, wd, counts, base, tile_e, tile_m, ybuf);
    combine_kernel<<<NT, 256, 0, stream>>>(ybuf, toppos, out);
}